// Round 12
// baseline (5906.838 us; speedup 1.0000x reference)
//
#include <hip/hip_runtime.h>
#include <hip/hip_bf16.h>
#include <math.h>

#define T_STEPS 512
#define BATCH   64
#define INDIM   1024
#define HDIM    1024
#define NWG     128      // persistent compute WGs; each owns 8 hidden cols

using bf16x8 = __attribute__((ext_vector_type(8))) __bf16;
using f32x4  = __attribute__((ext_vector_type(4))) float;
typedef unsigned long long u64;

#define HSLOT 16384      // u64 per h slot (128KB)

struct WP {
    const float* wx[4];
    const float* wh[4];
    const float* bx[4];
    const float* bh[4];
};

// Pack 8 weight matrices into combined bf16 [4H][K] layouts + combined bias.
__global__ void pack_weights(WP p, __hip_bfloat16* __restrict__ Wx,
                             __hip_bfloat16* __restrict__ Wh, float* __restrict__ bias)
{
    int i = blockIdx.x * blockDim.x + threadIdx.x;
    const int stride = gridDim.x * blockDim.x;
    const int total = 4 * HDIM * INDIM;
    for (int idx = i; idx < total; idx += stride) {
        int g = idx >> 20;
        int r = idx & ((1 << 20) - 1);
        Wx[idx] = __float2bfloat16(p.wx[g][r]);
        Wh[idx] = __float2bfloat16(p.wh[g][r]);
    }
    if (i < 4 * HDIM) {
        int g = i >> 10, r = i & 1023;
        bias[i] = p.bx[g][r] + p.bh[g][r];
    }
}

__global__ void cast_f32_bf16(const float* __restrict__ in,
                              __hip_bfloat16* __restrict__ out, int n4)
{
    int i = blockIdx.x * blockDim.x + threadIdx.x;
    const int stride = gridDim.x * blockDim.x;
    for (; i < n4; i += stride) {
        float4 v = ((const float4*)in)[i];
        union { __hip_bfloat16 b[4]; short4 s; } u;
        u.b[0] = __float2bfloat16(v.x);
        u.b[1] = __float2bfloat16(v.y);
        u.b[2] = __float2bfloat16(v.z);
        u.b[3] = __float2bfloat16(v.w);
        ((short4*)out)[i] = u.s;
    }
}

// h slot 0 init: MFMA-fragment-packed layout (R10-proven mapping).
// hx[slot][ ((w*8+kk)*4+m) ][lane][8 bf16]:
//   element = h[16m + (l&15)][256w + 32kk + 8*(l>>4) + i]
__global__ void init_state(const float* __restrict__ H0, const float* __restrict__ C0,
                           __hip_bfloat16* __restrict__ hx, float* __restrict__ c)
{
    int i = blockIdx.x * blockDim.x + threadIdx.x;
    if (i < BATCH * HDIM) {
        int b = i >> 10, j = i & 1023;
        int m = b >> 4, rA = b & 15;
        int wv = j >> 8, kk = (j >> 5) & 7, lhi = (j >> 3) & 3, ii = j & 7;
        size_t idx = ((((size_t)(wv << 3) + kk) << 2) + m) * 512
                   + (((lhi << 4) + rA) << 3) + ii;
        hx[idx] = __float2bfloat16(H0[i]);
        c[i] = C0[i];
    }
}

__global__ void epilogue(const float* __restrict__ lasth, const float* __restrict__ c,
                         float* __restrict__ Hf, float* __restrict__ Cf)
{
    int i = blockIdx.x * blockDim.x + threadIdx.x;
    if (i < BATCH * HDIM) {
        Hf[i] = lasth[i];
        Cf[i] = c[i];
    }
}

// xproj GEMM, M=128 tile (2 timesteps per WG): halves Wx panel re-reads.
// Grid (TC/2, 32). Per WG: M=128 rows of flattened [TC*64], N=128.
__global__ __launch_bounds__(256, 2) void xproj_gemm(
    const __hip_bfloat16* __restrict__ xb,   // chunk base [TC*64][1024]
    const __hip_bfloat16* __restrict__ Wx,   // [4096][1024]
    float* __restrict__ xp)                  // [TC][4096][64]
{
    __shared__ float ct[4][128][32];         // 64KB; reads conflict-free
    const int t = blockIdx.x;                // timestep PAIR
    const int n0 = blockIdx.y << 7;
    const int tid = threadIdx.x, w = tid >> 6, lane = tid & 63;
    const int rA = lane & 15, kg = (lane >> 4) << 3;
    const int nw = n0 + (w << 5);
    f32x4 acc[2][8] = {};
    const __hip_bfloat16* Arow = xb + (((size_t)t << 7) + rA) * 1024 + kg;
    const __hip_bfloat16* Brow = Wx + ((size_t)(nw + rA) << 10) + kg;
#pragma unroll 2
    for (int kk = 0; kk < 32; ++kk) {
        const int kb = kk << 5;
        bf16x8 bf0 = *reinterpret_cast<const bf16x8*>(Brow + kb);
        bf16x8 bf1 = *reinterpret_cast<const bf16x8*>(Brow + (16 << 10) + kb);
#pragma unroll
        for (int m = 0; m < 8; ++m) {
            bf16x8 af = *reinterpret_cast<const bf16x8*>(Arow + (m << 14) + kb);
            acc[0][m] = __builtin_amdgcn_mfma_f32_16x16x32_bf16(af, bf0, acc[0][m], 0, 0, 0);
            acc[1][m] = __builtin_amdgcn_mfma_f32_16x16x32_bf16(af, bf1, acc[1][m], 0, 0, 0);
        }
    }
#pragma unroll
    for (int n2 = 0; n2 < 2; ++n2)
#pragma unroll
        for (int m = 0; m < 8; ++m) {
            const int bb = (m << 4) + ((lane >> 4) << 2);
#pragma unroll
            for (int r = 0; r < 4; ++r)
                ct[w][bb + r][(n2 << 4) + rA] = acc[n2][m][r];
        }
    __syncthreads();
    const int n = lane & 31, mh = lane >> 5;   // mh: even/odd timestep of the pair
    float* obase = xp + (((size_t)(t << 1) + mh) * 4096 + nw + n) * 64;
#pragma unroll
    for (int j = 0; j < 16; ++j) {
        const int m0 = (mh << 6) + (j << 2);
        *reinterpret_cast<float4*>(obase + (j << 2)) = make_float4(
            ct[w][m0 + 0][n], ct[w][m0 + 1][n], ct[w][m0 + 2][n], ct[w][m0 + 3][n]);
    }
}

// Fence-free distributed-flag barrier (R6/R10-proven, byte-identical).
__device__ __forceinline__ void gbar_nofence(unsigned* flags, unsigned target)
{
    __syncthreads();                         // vmcnt(0): h atomics acked at MALL
    if (threadIdx.x == 0)
        __hip_atomic_store(&flags[(int)blockIdx.x * 16], target,
                           __ATOMIC_RELAXED, __HIP_MEMORY_SCOPE_AGENT);
    if (threadIdx.x < 64) {
        const unsigned* f0 = &flags[threadIdx.x * 16];
        const unsigned* f1 = &flags[(threadIdx.x + 64) * 16];
        int guard = 1 << 18;
        while ((__hip_atomic_load(f0, __ATOMIC_RELAXED, __HIP_MEMORY_SCOPE_AGENT) < target ||
                __hip_atomic_load(f1, __ATOMIC_RELAXED, __HIP_MEMORY_SCOPE_AGENT) < target)
               && --guard > 0)
            __builtin_amdgcn_s_sleep(2);
    }
    __syncthreads();
}

__device__ __forceinline__ float fast_sigmoid(float x)
{
    return 1.f / (1.f + __expf(-x));
}
__device__ __forceinline__ float fast_tanh(float x)
{
    x = fminf(15.f, fmaxf(-15.f, x));
    const float e = __expf(2.f * x);
    return (e - 1.f) / (e + 1.f);
}

// Persistent recurrence. Grid = NWG(128) x 256 threads.
// h exchange: STEP-UNIQUE slots (hx[s], write slot (s+1)%TC). Every h
// address is written exactly once per kernel launch (relaxed agent atomic,
// MALL write-through) and read only after the flag barrier -> no XCD L2
// can hold a stale copy -> h LOADS are plain cached loads, L2-shared by
// the 16 WGs of each XCD (MALL broadcast 16MB -> ~1MB/step). Cross-launch
// staleness is cleared by the HSA dispatch-boundary cache invalidate.
// No fences anywhere.
__global__ __launch_bounds__(256, 1) void lstm_persist(
    const float* __restrict__ xp,            // [TC][4096][64]
    const __hip_bfloat16* __restrict__ Wh,   // [4096][1024]
    const float* __restrict__ bias,          // [4096]
    u64* __restrict__ hx,                    // [TC][HSLOT] packed h slots
    float* __restrict__ cbuf,                // [64][1024]
    float* __restrict__ out,                 // [TC][64][1024]
    unsigned* __restrict__ flags,            // [NWG*16]
    unsigned stepBase,
    int TC)
{
    __shared__ float gl[4][64][33];          // per-wave partials [w][b][r<32]
    __shared__ float hs[64][9];              // gathered h f32

    const int tid  = threadIdx.x;
    const int w    = tid >> 6;
    const int lane = tid & 63;
    const int rA   = lane & 15;
    const int j0   = blockIdx.x << 3;

    // Wave's Wh fragments: its K-quarter of the WG's 32 gate-rows.
    const int kg = (lane >> 4) << 3;
    bf16x8 whf[2][8];
#pragma unroll
    for (int n2 = 0; n2 < 2; ++n2) {
        const int row  = (n2 << 4) + rA;
        const int grow = ((row >> 3) << 10) + j0 + (row & 7);
        const __hip_bfloat16* wr = Wh + ((size_t)grow << 10) + (w << 8) + kg;
#pragma unroll
        for (int kk = 0; kk < 8; ++kk)
            whf[n2][kk] = *reinterpret_cast<const bf16x8*>(wr + (kk << 5));
    }

    // Gate-phase persistent state: thread (b=lane, cols cl=w*2+{0,1})
    const int b = lane;
    float creg[2], brg[2][4];
#pragma unroll
    for (int e = 0; e < 2; ++e) {
        const int cl = (w << 1) + e;
        creg[e] = cbuf[(b << 10) + j0 + cl];
#pragma unroll
        for (int g = 0; g < 4; ++g) brg[e][g] = bias[(g << 10) + j0 + cl];
    }

    // Producer store base (u64 units): WG bw -> triple (wc,kkc,lhi).
    const int bw  = blockIdx.x;
    const int pblk = (((bw >> 5) << 3) + ((bw >> 2) & 7)) << 2;   // (wc*8+kkc)*4

#define LOAD_XV(dst, sidx)                                                     \
    do {                                                                       \
        const float* xpt_ = xp + (size_t)(sidx) * 262144;                      \
        _Pragma("unroll") for (int e = 0; e < 2; ++e)                          \
        _Pragma("unroll") for (int g = 0; g < 4; ++g)                          \
            dst[e][g] = xpt_[(((g << 10) + j0 + (w << 1) + e) << 6) + b];      \
    } while (0)

    float xv[2][4];
    LOAD_XV(xv, 0);

    for (int s = 0; s < TC; ++s) {
        const u64* hp = hx + (size_t)s * HSLOT;
        u64*       hn = hx + (size_t)((s + 1 == TC) ? 0 : s + 1) * HSLOT;

        // Prefetch next step's xproj (latency hides under GEMM+wait).
        float xn[2][4];
        if (s + 1 < TC) LOAD_XV(xn, s + 1);

        // h-GEMM: this wave's K-quarter. PLAIN cached 16B loads (packed
        // layout -> lane-contiguous; L2-shared across the XCD's 16 WGs).
        f32x4 acc[2][4] = {};
#pragma unroll
        for (int hhalf = 0; hhalf < 2; ++hhalf) {
            bf16x8 av[4][4];
#pragma unroll
            for (int k2 = 0; k2 < 4; ++k2) {
                const int kk = (hhalf << 2) + k2;
#pragma unroll
                for (int m = 0; m < 4; ++m)
                    av[k2][m] = *reinterpret_cast<const bf16x8*>(
                        hp + ((((size_t)(w << 3) + kk) << 2) + m) * 128 + (lane << 1));
            }
#pragma unroll
            for (int k2 = 0; k2 < 4; ++k2) {
                const int kk = (hhalf << 2) + k2;
#pragma unroll
                for (int m = 0; m < 4; ++m)
#pragma unroll
                    for (int n2 = 0; n2 < 2; ++n2)
                        acc[n2][m] = __builtin_amdgcn_mfma_f32_16x16x32_bf16(
                            av[k2][m], whf[n2][kk], acc[n2][m], 0, 0, 0);
            }
        }

        // Partials: C/D layout col=lane&15, row=(lane>>4)*4+r
#pragma unroll
        for (int n2 = 0; n2 < 2; ++n2)
#pragma unroll
            for (int m = 0; m < 4; ++m) {
                const int bb = (m << 4) + ((lane >> 4) << 2);
#pragma unroll
                for (int r = 0; r < 4; ++r)
                    gl[w][bb + r][(n2 << 4) + rA] = acc[n2][m][r];
            }
        __syncthreads();

        // Gates: thread (b, cl=w*2+e); write h row fragments to LDS.
#pragma unroll
        for (int e = 0; e < 2; ++e) {
            const int cl = (w << 1) + e;
            float gv[4];
#pragma unroll
            for (int g = 0; g < 4; ++g)
                gv[g] = gl[0][b][(g << 3) + cl] + gl[1][b][(g << 3) + cl]
                      + gl[2][b][(g << 3) + cl] + gl[3][b][(g << 3) + cl]
                      + brg[e][g] + xv[e][g];
            const float i_ = fast_sigmoid(gv[0]);
            const float f_ = fast_sigmoid(gv[1]);
            const float o_ = fast_sigmoid(gv[2]);
            const float ct = fast_tanh(gv[3]);
            const float cn = f_ * creg[e] + i_ * ct;
            creg[e] = cn;
            hs[b][cl] = o_ * fast_tanh(cn);
        }
        __syncthreads();

        // Row stores (tid<64 = batch row): out f32 (plain) + packed h
        // (relaxed agent atomic write-through, coalesced 256B / 16 threads).
        if (tid < 64) {
            float v[8];
#pragma unroll
            for (int k = 0; k < 8; ++k) v[k] = hs[tid][k];
            float* orow = out + (((size_t)s << 6) + tid) * 1024 + j0;
            *reinterpret_cast<float4*>(orow)     = make_float4(v[0], v[1], v[2], v[3]);
            *reinterpret_cast<float4*>(orow + 4) = make_float4(v[4], v[5], v[6], v[7]);
            union { __hip_bfloat16 bh[8]; u64 q[2]; } u;
#pragma unroll
            for (int k = 0; k < 8; ++k) u.bh[k] = __float2bfloat16(v[k]);
            u64* hq = hn + ((size_t)(pblk + (tid >> 4))) * 128
                         + ((((bw & 3) << 4) + (tid & 15)) << 1);
            __hip_atomic_store(hq,     u.q[0], __ATOMIC_RELAXED, __HIP_MEMORY_SCOPE_AGENT);
            __hip_atomic_store(hq + 1, u.q[1], __ATOMIC_RELAXED, __HIP_MEMORY_SCOPE_AGENT);
        }
        gbar_nofence(flags, stepBase + (unsigned)(s + 1));

#pragma unroll
        for (int e = 0; e < 2; ++e)
#pragma unroll
            for (int g = 0; g < 4; ++g)
                xv[e][g] = xn[e][g];
    }

    // Persist c for next chunk / epilogue.
#pragma unroll
    for (int e = 0; e < 2; ++e)
        cbuf[(b << 10) + j0 + (w << 1) + e] = creg[e];
}

extern "C" void kernel_launch(void* const* d_in, const int* in_sizes, int n_in,
                              void* d_out, int out_size, void* d_ws, size_t ws_size,
                              hipStream_t stream)
{
    const float* inputs = (const float*)d_in[0];
    const float* H0     = (const float*)d_in[1];
    const float* C0     = (const float*)d_in[2];

    WP wp;
    wp.wx[0] = (const float*)d_in[3];  wp.bx[0] = (const float*)d_in[4];
    wp.wh[0] = (const float*)d_in[5];  wp.bh[0] = (const float*)d_in[6];
    wp.wx[1] = (const float*)d_in[7];  wp.bx[1] = (const float*)d_in[8];
    wp.wh[1] = (const float*)d_in[9];  wp.bh[1] = (const float*)d_in[10];
    wp.wx[2] = (const float*)d_in[11]; wp.bx[2] = (const float*)d_in[12];
    wp.wh[2] = (const float*)d_in[13]; wp.bh[2] = (const float*)d_in[14];
    wp.wx[3] = (const float*)d_in[15]; wp.bx[3] = (const float*)d_in[16];
    wp.wh[3] = (const float*)d_in[17]; wp.bh[3] = (const float*)d_in[18];

    char* ws = (char*)d_ws;
    size_t off = 0;
    auto alloc = [&](size_t bytes) {
        void* p = ws + off;
        off = (off + bytes + 255) & ~(size_t)255;
        return p;
    };
    __hip_bfloat16* Wx   = (__hip_bfloat16*)alloc((size_t)4 * HDIM * INDIM * 2);
    __hip_bfloat16* Wh   = (__hip_bfloat16*)alloc((size_t)4 * HDIM * HDIM * 2);
    float*          bias = (float*)alloc((size_t)4 * HDIM * 4);
    __hip_bfloat16* xb   = (__hip_bfloat16*)alloc((size_t)T_STEPS * BATCH * INDIM * 2);
    float*          cbuf = (float*)alloc((size_t)BATCH * HDIM * 4);
    unsigned*       flags= (unsigned*)alloc((size_t)NWG * 16 * 4);

    // Per-step: 1MB xp + 128KB hx. Pick largest chunk that fits.
    const size_t per_t = (size_t)4 * HDIM * BATCH * 4;
    const size_t per_h = (size_t)HSLOT * 8;
    int TC = 0;
    for (int tc : {512, 256, 128, 64, 32, 16})
        if (off + (size_t)tc * (per_t + per_h) + 512 <= ws_size) { TC = tc; break; }
    if (TC == 0) return;
    u64*   hx = (u64*)alloc((size_t)TC * per_h);
    float* xp = (float*)alloc((size_t)TC * per_t);

    float* out = (float*)d_out;

    hipMemsetAsync(flags, 0, (size_t)NWG * 16 * 4, stream);  // deterministic replays
    hipLaunchKernelGGL(pack_weights, dim3(2048), dim3(256), 0, stream, wp, Wx, Wh, bias);
    hipLaunchKernelGGL(cast_f32_bf16, dim3(2048), dim3(256), 0, stream,
                       inputs, xb, T_STEPS * BATCH * INDIM / 4);
    hipLaunchKernelGGL(init_state, dim3(256), dim3(256), 0, stream,
                       H0, C0, (__hip_bfloat16*)hx, cbuf);

    unsigned stepBase = 0;
    for (int t0 = 0; t0 < T_STEPS; t0 += TC) {
        hipLaunchKernelGGL(xproj_gemm, dim3(TC / 2, 32), dim3(256), 0, stream,
                           xb + (size_t)t0 * BATCH * INDIM, Wx, xp);
        hipLaunchKernelGGL(lstm_persist, dim3(NWG), dim3(256), 0, stream,
                           (const float*)xp, (const __hip_bfloat16*)Wh,
                           (const float*)bias, hx, cbuf,
                           out + (size_t)t0 * BATCH * HDIM, flags, stepBase, TC);
        stepBase += (unsigned)TC;
    }
    hipLaunchKernelGGL(epilogue, dim3(256), dim3(256), 0, stream,
                       out + (size_t)(T_STEPS - 1) * BATCH * HDIM, cbuf,
                       out + (size_t)T_STEPS * BATCH * HDIM,
                       out + (size_t)T_STEPS * BATCH * HDIM + BATCH * HDIM);
}

// Round 14
// 4280.932 us; speedup vs baseline: 1.3798x; 1.3798x over previous
//
#include <hip/hip_runtime.h>
#include <hip/hip_bf16.h>
#include <math.h>

#define T_STEPS 512
#define BATCH   64
#define INDIM   1024
#define HDIM    1024
#define NWG     128      // persistent compute WGs; each owns 8 hidden cols
#define HSLOT   16384    // u64 per h slot (128KB); 4-slot ring

using bf16x8 = __attribute__((ext_vector_type(8))) __bf16;
using f32x4  = __attribute__((ext_vector_type(4))) float;
typedef unsigned long long u64;

struct WP {
    const float* wx[4];
    const float* wh[4];
    const float* bx[4];
    const float* bh[4];
};

// Pack 8 weight matrices into combined bf16 [4H][K] layouts + combined bias.
__global__ void pack_weights(WP p, __hip_bfloat16* __restrict__ Wx,
                             __hip_bfloat16* __restrict__ Wh, float* __restrict__ bias)
{
    int i = blockIdx.x * blockDim.x + threadIdx.x;
    const int stride = gridDim.x * blockDim.x;
    const int total = 4 * HDIM * INDIM;
    for (int idx = i; idx < total; idx += stride) {
        int g = idx >> 20;
        int r = idx & ((1 << 20) - 1);
        Wx[idx] = __float2bfloat16(p.wx[g][r]);
        Wh[idx] = __float2bfloat16(p.wh[g][r]);
    }
    if (i < 4 * HDIM) {
        int g = i >> 10, r = i & 1023;
        bias[i] = p.bx[g][r] + p.bh[g][r];
    }
}

__global__ void cast_f32_bf16(const float* __restrict__ in,
                              __hip_bfloat16* __restrict__ out, int n4)
{
    int i = blockIdx.x * blockDim.x + threadIdx.x;
    const int stride = gridDim.x * blockDim.x;
    for (; i < n4; i += stride) {
        float4 v = ((const float4*)in)[i];
        union { __hip_bfloat16 b[4]; short4 s; } u;
        u.b[0] = __float2bfloat16(v.x);
        u.b[1] = __float2bfloat16(v.y);
        u.b[2] = __float2bfloat16(v.z);
        u.b[3] = __float2bfloat16(v.w);
        ((short4*)out)[i] = u.s;
    }
}

// h slot 0 init: MFMA-fragment-packed layout (R10-proven mapping).
// hx[slot][ ((w*8+kk)*4+m) ][lane][8 bf16]:
//   element = h[16m + (l&15)][256w + 32kk + 8*(l>>4) + i]
__global__ void init_state(const float* __restrict__ H0, const float* __restrict__ C0,
                           __hip_bfloat16* __restrict__ hx, float* __restrict__ c)
{
    int i = blockIdx.x * blockDim.x + threadIdx.x;
    if (i < BATCH * HDIM) {
        int b = i >> 10, j = i & 1023;
        int m = b >> 4, rA = b & 15;
        int wv = j >> 8, kk = (j >> 5) & 7, lhi = (j >> 3) & 3, ii = j & 7;
        size_t idx = ((((size_t)(wv << 3) + kk) << 2) + m) * 512
                   + (((lhi << 4) + rA) << 3) + ii;
        hx[idx] = __float2bfloat16(H0[i]);
        c[i] = C0[i];
    }
}

__global__ void epilogue(const float* __restrict__ lasth, const float* __restrict__ c,
                         float* __restrict__ Hf, float* __restrict__ Cf)
{
    int i = blockIdx.x * blockDim.x + threadIdx.x;
    if (i < BATCH * HDIM) {
        Hf[i] = lasth[i];
        Cf[i] = c[i];
    }
}

// xproj GEMM, M=128 tile (2 timesteps per WG) - R12-proven.
__global__ __launch_bounds__(256, 2) void xproj_gemm(
    const __hip_bfloat16* __restrict__ xb,   // chunk base [TC*64][1024]
    const __hip_bfloat16* __restrict__ Wx,   // [4096][1024]
    float* __restrict__ xp)                  // [TC][4096][64]
{
    __shared__ float ct[4][128][32];
    const int t = blockIdx.x;                // timestep PAIR
    const int n0 = blockIdx.y << 7;
    const int tid = threadIdx.x, w = tid >> 6, lane = tid & 63;
    const int rA = lane & 15, kg = (lane >> 4) << 3;
    const int nw = n0 + (w << 5);
    f32x4 acc[2][8] = {};
    const __hip_bfloat16* Arow = xb + (((size_t)t << 7) + rA) * 1024 + kg;
    const __hip_bfloat16* Brow = Wx + ((size_t)(nw + rA) << 10) + kg;
#pragma unroll 2
    for (int kk = 0; kk < 32; ++kk) {
        const int kb = kk << 5;
        bf16x8 bf0 = *reinterpret_cast<const bf16x8*>(Brow + kb);
        bf16x8 bf1 = *reinterpret_cast<const bf16x8*>(Brow + (16 << 10) + kb);
#pragma unroll
        for (int m = 0; m < 8; ++m) {
            bf16x8 af = *reinterpret_cast<const bf16x8*>(Arow + (m << 14) + kb);
            acc[0][m] = __builtin_amdgcn_mfma_f32_16x16x32_bf16(af, bf0, acc[0][m], 0, 0, 0);
            acc[1][m] = __builtin_amdgcn_mfma_f32_16x16x32_bf16(af, bf1, acc[1][m], 0, 0, 0);
        }
    }
#pragma unroll
    for (int n2 = 0; n2 < 2; ++n2)
#pragma unroll
        for (int m = 0; m < 8; ++m) {
            const int bb = (m << 4) + ((lane >> 4) << 2);
#pragma unroll
            for (int r = 0; r < 4; ++r)
                ct[w][bb + r][(n2 << 4) + rA] = acc[n2][m][r];
        }
    __syncthreads();
    const int n = lane & 31, mh = lane >> 5;
    float* obase = xp + (((size_t)(t << 1) + mh) * 4096 + nw + n) * 64;
#pragma unroll
    for (int j = 0; j < 16; ++j) {
        const int m0 = (mh << 6) + (j << 2);
        *reinterpret_cast<float4*>(obase + (j << 2)) = make_float4(
            ct[w][m0 + 0][n], ct[w][m0 + 1][n], ct[w][m0 + 2][n], ct[w][m0 + 3][n]);
    }
}

__device__ __forceinline__ float fast_sigmoid(float x)
{
    return 1.f / (1.f + __expf(-x));
}
__device__ __forceinline__ float fast_tanh(float x)
{
    x = fminf(15.f, fmaxf(-15.f, x));
    const float e = __expf(2.f * x);
    return (e - 1.f) / (e + 1.f);
}

// Persistent recurrence. Grid = NWG(128) x 256 threads.
// Per-wave quarter-flag sync: wave w of every WG consumes h cols
// [256w,256w+256) = exactly the output of WGs [32w,32w+32). At the top of
// step t each wave polls ITS 32 producer flags (>= t), then loads its
// quarter (R10 MALL-atomic coalesced loads) and MFMAs. The LDS-reduce
// syncthreads re-couples the 4 waves. Flags are monotone step counters
// posted once per step after a drain-sync -> deadlock-free; WG skew is
// provably <=1 step, so a 4-slot h ring (slot = abs_step & 3) removes all
// WAR hazards. Gates store h DIRECTLY as packed-u32 relaxed agent atomics
// (no LDS gather on the h path); out[] stores happen after the flag post.
__global__ __launch_bounds__(256, 1) void lstm_persist(
    const float* __restrict__ xp,            // [TC][4096][64]
    const __hip_bfloat16* __restrict__ Wh,   // [4096][1024]
    const float* __restrict__ bias,          // [4096]
    u64* __restrict__ hx,                    // [4][HSLOT] packed h ring
    float* __restrict__ cbuf,                // [64][1024]
    float* __restrict__ out,                 // [TC][64][1024]
    unsigned* __restrict__ flags,            // [NWG*16]
    unsigned stepBase,
    int TC)
{
    __shared__ float gl[4][64][33];          // per-wave partials [w][b][r<32]
    __shared__ float hs[64][9];              // h f32 (for out stores only)

    const int tid  = threadIdx.x;
    const int w    = tid >> 6;
    const int lane = tid & 63;
    const int rA   = lane & 15;
    const int j0   = blockIdx.x << 3;

    // Wave's Wh fragments: its K-quarter of the WG's 32 gate-rows.
    const int kg = (lane >> 4) << 3;
    bf16x8 whf[2][8];
#pragma unroll
    for (int n2 = 0; n2 < 2; ++n2) {
        const int row  = (n2 << 4) + rA;
        const int grow = ((row >> 3) << 10) + j0 + (row & 7);
        const __hip_bfloat16* wr = Wh + ((size_t)grow << 10) + (w << 8) + kg;
#pragma unroll
        for (int kk = 0; kk < 8; ++kk)
            whf[n2][kk] = *reinterpret_cast<const bf16x8*>(wr + (kk << 5));
    }

    // Gate-phase persistent state: thread (b=lane, cols cl=w*2+{0,1})
    const int b = lane;
    float creg[2], brg[2][4];
#pragma unroll
    for (int e = 0; e < 2; ++e) {
        const int cl = (w << 1) + e;
        creg[e] = cbuf[(b << 10) + j0 + cl];
#pragma unroll
        for (int g = 0; g < 4; ++g) brg[e][g] = bias[(g << 10) + j0 + cl];
    }

    // Producer store base: WG bw -> triple (wc,kkc,lhi). u32 view for gates.
    const int bw   = blockIdx.x;
    const int pblk = (((bw >> 5) << 3) + ((bw >> 2) & 7)) << 2;   // (wc*8+kkc)*4
    // gate thread's u32 index within a slot (block term added per-step):
    const unsigned gsto = (unsigned)(pblk + (b >> 4)) * 256
                        + (unsigned)((((bw & 3) << 4) + (b & 15)) << 2) + w;
    // this wave's producer flag to poll:
    const unsigned* fq = flags + (((w << 5) + (lane & 31)) << 4);

#define LOAD_XV(dst, sidx)                                                     \
    do {                                                                       \
        const float* xpt_ = xp + (size_t)(sidx) * 262144;                      \
        _Pragma("unroll") for (int e = 0; e < 2; ++e)                          \
        _Pragma("unroll") for (int g = 0; g < 4; ++g)                          \
            dst[e][g] = xpt_[(((g << 10) + j0 + (w << 1) + e) << 6) + b];      \
    } while (0)

    float xv[2][4];
    LOAD_XV(xv, 0);

    for (int s = 0; s < TC; ++s) {
        const unsigned t = stepBase + (unsigned)s;
        const u64* hp = hx + (size_t)(t & 3) * HSLOT;
        u64*       hn = hx + (size_t)((t + 1) & 3) * HSLOT;

        // Prefetch next step's xproj (independent of h).
        float xn[2][4];
        if (s + 1 < TC) LOAD_XV(xn, s + 1);

        // Per-wave wait: this wave's 32 quarter-producers at step t.
        {
            int guard = 1 << 18;
            while (--guard > 0) {
                unsigned v = __hip_atomic_load(fq, __ATOMIC_RELAXED, __HIP_MEMORY_SCOPE_AGENT);
                if (__all((int)(v >= t))) break;
                __builtin_amdgcn_s_sleep(1);
            }
        }

        // h-GEMM: this wave's K-quarter (R10 MALL-atomic coalesced loads).
        f32x4 acc[2][4] = {};
#pragma unroll
        for (int hhalf = 0; hhalf < 2; ++hhalf) {
            u64 aq[4][4][2];
#pragma unroll
            for (int k2 = 0; k2 < 4; ++k2) {
                const int kk = (hhalf << 2) + k2;
#pragma unroll
                for (int m = 0; m < 4; ++m) {
                    const u64* p = hp + ((((size_t)(w << 3) + kk) << 2) + m) * 128
                                     + (lane << 1);
                    aq[k2][m][0] = __hip_atomic_load(p,     __ATOMIC_RELAXED, __HIP_MEMORY_SCOPE_AGENT);
                    aq[k2][m][1] = __hip_atomic_load(p + 1, __ATOMIC_RELAXED, __HIP_MEMORY_SCOPE_AGENT);
                }
            }
#pragma unroll
            for (int k2 = 0; k2 < 4; ++k2) {
                const int kk = (hhalf << 2) + k2;
#pragma unroll
                for (int m = 0; m < 4; ++m) {
                    union { u64 q[2]; bf16x8 v; } c;
                    c.q[0] = aq[k2][m][0];
                    c.q[1] = aq[k2][m][1];
#pragma unroll
                    for (int n2 = 0; n2 < 2; ++n2)
                        acc[n2][m] = __builtin_amdgcn_mfma_f32_16x16x32_bf16(
                            c.v, whf[n2][kk], acc[n2][m], 0, 0, 0);
                }
            }
        }

        // Partials: C/D layout col=lane&15, row=(lane>>4)*4+r
#pragma unroll
        for (int n2 = 0; n2 < 2; ++n2)
#pragma unroll
            for (int m = 0; m < 4; ++m) {
                const int bb = (m << 4) + ((lane >> 4) << 2);
#pragma unroll
                for (int r = 0; r < 4; ++r)
                    gl[w][bb + r][(n2 << 4) + rA] = acc[n2][m][r];
            }
        __syncthreads();

        // Gates: thread (b, cl=w*2+e). h stored DIRECTLY (packed u32 atomic,
        // both cols adjacent in the packed layout). hs kept only for out[].
        {
            float hv[2];
#pragma unroll
            for (int e = 0; e < 2; ++e) {
                const int cl = (w << 1) + e;
                float gv[4];
#pragma unroll
                for (int g = 0; g < 4; ++g)
                    gv[g] = gl[0][b][(g << 3) + cl] + gl[1][b][(g << 3) + cl]
                          + gl[2][b][(g << 3) + cl] + gl[3][b][(g << 3) + cl]
                          + brg[e][g] + xv[e][g];
                const float i_ = fast_sigmoid(gv[0]);
                const float f_ = fast_sigmoid(gv[1]);
                const float o_ = fast_sigmoid(gv[2]);
                const float ct = fast_tanh(gv[3]);
                const float cn = f_ * creg[e] + i_ * ct;
                creg[e] = cn;
                hv[e] = o_ * fast_tanh(cn);
                hs[b][cl] = hv[e];
            }
            union { __hip_bfloat16 bh[2]; unsigned u; } pk;
            pk.bh[0] = __float2bfloat16(hv[0]);
            pk.bh[1] = __float2bfloat16(hv[1]);
            __hip_atomic_store((unsigned*)hn + gsto, pk.u,
                               __ATOMIC_RELAXED, __HIP_MEMORY_SCOPE_AGENT);
        }
        __syncthreads();                     // all waves' h stores acked at MALL

        // Publish this WG's flag; out stores AFTER (off critical path).
        if (tid == 0)
            __hip_atomic_store(&flags[bw * 16], t + 1,
                               __ATOMIC_RELAXED, __HIP_MEMORY_SCOPE_AGENT);
        if (tid < 64) {
            float v[8];
#pragma unroll
            for (int k = 0; k < 8; ++k) v[k] = hs[tid][k];
            float* orow = out + (((size_t)s << 6) + tid) * 1024 + j0;
            *reinterpret_cast<float4*>(orow)     = make_float4(v[0], v[1], v[2], v[3]);
            *reinterpret_cast<float4*>(orow + 4) = make_float4(v[4], v[5], v[6], v[7]);
        }

#pragma unroll
        for (int e = 0; e < 2; ++e)
#pragma unroll
            for (int g = 0; g < 4; ++g)
                xv[e][g] = xn[e][g];
    }

    // Persist c for next chunk / epilogue.
#pragma unroll
    for (int e = 0; e < 2; ++e)
        cbuf[(b << 10) + j0 + (w << 1) + e] = creg[e];
}

extern "C" void kernel_launch(void* const* d_in, const int* in_sizes, int n_in,
                              void* d_out, int out_size, void* d_ws, size_t ws_size,
                              hipStream_t stream)
{
    const float* inputs = (const float*)d_in[0];
    const float* H0     = (const float*)d_in[1];
    const float* C0     = (const float*)d_in[2];

    WP wp;
    wp.wx[0] = (const float*)d_in[3];  wp.bx[0] = (const float*)d_in[4];
    wp.wh[0] = (const float*)d_in[5];  wp.bh[0] = (const float*)d_in[6];
    wp.wx[1] = (const float*)d_in[7];  wp.bx[1] = (const float*)d_in[8];
    wp.wh[1] = (const float*)d_in[9];  wp.bh[1] = (const float*)d_in[10];
    wp.wx[2] = (const float*)d_in[11]; wp.bx[2] = (const float*)d_in[12];
    wp.wh[2] = (const float*)d_in[13]; wp.bh[2] = (const float*)d_in[14];
    wp.wx[3] = (const float*)d_in[15]; wp.bx[3] = (const float*)d_in[16];
    wp.wh[3] = (const float*)d_in[17]; wp.bh[3] = (const float*)d_in[18];

    char* ws = (char*)d_ws;
    size_t off = 0;
    auto alloc = [&](size_t bytes) {
        void* p = ws + off;
        off = (off + bytes + 255) & ~(size_t)255;
        return p;
    };
    __hip_bfloat16* Wx   = (__hip_bfloat16*)alloc((size_t)4 * HDIM * INDIM * 2);
    __hip_bfloat16* Wh   = (__hip_bfloat16*)alloc((size_t)4 * HDIM * HDIM * 2);
    float*          bias = (float*)alloc((size_t)4 * HDIM * 4);
    __hip_bfloat16* xb   = (__hip_bfloat16*)alloc((size_t)T_STEPS * BATCH * INDIM * 2);
    u64*            hx   = (u64*)alloc((size_t)4 * HSLOT * 8);   // 4-slot ring
    float*          cbuf = (float*)alloc((size_t)BATCH * HDIM * 4);
    unsigned*       flags= (unsigned*)alloc((size_t)NWG * 16 * 4);

    const size_t per_t = (size_t)4 * HDIM * BATCH * 4;
    int TC = 0;
    for (int tc : {512, 256, 128, 64, 32, 16})
        if (off + (size_t)tc * per_t <= ws_size) { TC = tc; break; }
    if (TC == 0) return;
    float* xp = (float*)alloc((size_t)TC * per_t);

    float* out = (float*)d_out;

    hipMemsetAsync(flags, 0, (size_t)NWG * 16 * 4, stream);  // deterministic replays
    hipLaunchKernelGGL(pack_weights, dim3(2048), dim3(256), 0, stream, wp, Wx, Wh, bias);
    hipLaunchKernelGGL(cast_f32_bf16, dim3(2048), dim3(256), 0, stream,
                       inputs, xb, T_STEPS * BATCH * INDIM / 4);
    hipLaunchKernelGGL(init_state, dim3(256), dim3(256), 0, stream,
                       H0, C0, (__hip_bfloat16*)hx, cbuf);

    unsigned stepBase = 0;
    for (int t0 = 0; t0 < T_STEPS; t0 += TC) {
        hipLaunchKernelGGL(xproj_gemm, dim3(TC / 2, 32), dim3(256), 0, stream,
                           xb + (size_t)t0 * BATCH * INDIM, Wx, xp);
        hipLaunchKernelGGL(lstm_persist, dim3(NWG), dim3(256), 0, stream,
                           (const float*)xp, (const __hip_bfloat16*)Wh,
                           (const float*)bias, hx, cbuf,
                           out + (size_t)t0 * BATCH * HDIM, flags, stepBase, TC);
        stepBase += (unsigned)TC;
    }
    hipLaunchKernelGGL(epilogue, dim3(256), dim3(256), 0, stream,
                       out + (size_t)(T_STEPS - 1) * BATCH * HDIM, cbuf,
                       out + (size_t)T_STEPS * BATCH * HDIM,
                       out + (size_t)T_STEPS * BATCH * HDIM + BATCH * HDIM);
}